// Round 1
// baseline (976.284 us; speedup 1.0000x reference)
//
#include <hip/hip_runtime.h>
#include <stdint.h>

#define B_ 16
#define H_ 1024
#define T_ 1500
#define MAXTOK 192
#define NCOL (B_*T_)        /* 24000 columns (b,t) */
#define KDIM (3*H_)         /* 3072 GEMM K */
#define TPAD 1502           /* T + 2 pad rows */
#define INV2T2 (1.0f/(2.0f*0.35f*0.35f))
#define LOSS_IDX (B_*MAXTOK*H_ + B_)
#define TOK_BASE (B_*MAXTOK*H_)

typedef __bf16 bf16x8 __attribute__((ext_vector_type(8)));
typedef float  f32x4  __attribute__((ext_vector_type(4)));

__device__ __forceinline__ unsigned short f2bf(float f) {
    unsigned int u = __float_as_uint(f);
    unsigned int r = (u + 0x7FFFu + ((u >> 16) & 1u)) >> 16;
    return (unsigned short)r;
}

// ---------------- init: zero accumulators, denoms, loss slot, Xt pad rows ----
__global__ void init_kernel(float* rawacc, float* denom, float* out, unsigned short* Xt) {
    int idx = blockIdx.x * blockDim.x + threadIdx.x;
    if (idx < NCOL) { rawacc[idx] = 0.f; return; }
    if (idx < NCOL + B_*MAXTOK) { denom[idx - NCOL] = 0.f; return; }
    if (idx == NCOL + B_*MAXTOK) { out[LOSS_IDX] = 0.f; return; }
    int j = idx - (NCOL + B_*MAXTOK + 1);
    if (j < B_*2048) {
        int b = j >> 11, r = j & 2047;
        long off = (long)b * TPAD * 1024 + ((r < 1024) ? r : (1501L*1024 + (r - 1024)));
        Xt[off] = 0;
    }
}

// ---------------- re-layout conv_w [h][i][k] -> bf16 Ar[h][k*1024 + i] -------
__global__ void precast_w(const float* __restrict__ cw, unsigned short* __restrict__ Ar) {
    int idx = blockIdx.x * blockDim.x + threadIdx.x;
    if (idx >= H_*KDIM) return;
    int h = idx / KDIM, rem = idx - h*KDIM;
    int k = rem >> 10, i = rem & 1023;
    Ar[idx] = f2bf(cw[h*KDIM + i*3 + k]);
}

// ---------------- transpose x [b][i][t] -> bf16 Xt[b][t+1][i] ---------------
__global__ void transpose_x(const float* __restrict__ x, unsigned short* __restrict__ Xt) {
    __shared__ float tile[32][33];
    int b = blockIdx.z;
    int t = blockIdx.x*32 + threadIdx.x;
    int i = blockIdx.y*32 + threadIdx.y;
    tile[threadIdx.y][threadIdx.x] = (t < T_) ? x[((long)b*H_ + i)*T_ + t] : 0.f;
    __syncthreads();
    int tt = blockIdx.x*32 + threadIdx.y;
    int ii = blockIdx.y*32 + threadIdx.x;
    if (tt < T_) Xt[((long)b*TPAD + tt + 1)*1024 + ii] = f2bf(tile[threadIdx.x][threadIdx.y]);
}

// ---------------- conv GEMM (bf16 MFMA) fused with silu*proj_w h-reduction ---
// C[h, bt] = sum_kk Ar[h,kk] * Xt[colbase(bt) + kk]; then
// rawacc[bt] += sum_{h in tile} proj_w[h] * silu(C + conv_b[h])
__global__ __launch_bounds__(256) void conv_gemm(
    const unsigned short* __restrict__ Ar, const unsigned short* __restrict__ Xt,
    const float* __restrict__ conv_b, const float* __restrict__ proj_w,
    float* __restrict__ rawacc)
{
    __shared__ unsigned short As[128*72];
    __shared__ unsigned short Bs[128*72];
    __shared__ float colsum[128];
    int tid = threadIdx.x;
    int n0 = blockIdx.x * 128;
    int h0 = blockIdx.y * 128;

    int srow = tid >> 3;          // 0..31
    int scol = (tid & 7) * 8;     // 0,8,...,56
    const unsigned short* asrc = Ar + (long)(h0 + srow) * KDIM + scol;
    long bbase[4]; bool bval[4];
    #pragma unroll
    for (int p = 0; p < 4; ++p) {
        int bt = n0 + p*32 + srow;
        bval[p] = (bt < NCOL);
        int bb = bval[p] ? (bt / T_) : 0;
        int t  = bval[p] ? (bt - bb*T_) : 0;
        bbase[p] = ((long)bb * TPAD + t) * 1024 + scol;
    }

    f32x4 acc[4][4];
    f32x4 zero = {0.f, 0.f, 0.f, 0.f};
    #pragma unroll
    for (int a = 0; a < 4; ++a)
        #pragma unroll
        for (int c = 0; c < 4; ++c) acc[a][c] = zero;

    int lane = tid & 63;
    int w = tid >> 6, wm = w >> 1, wn = w & 1;
    int quad = lane >> 4, l16 = lane & 15;

    for (int kt = 0; kt < KDIM/64; ++kt) {
        __syncthreads();
        #pragma unroll
        for (int p = 0; p < 4; ++p) {
            uint4 av = *(const uint4*)(asrc + (long)p*32*KDIM + kt*64);
            *(uint4*)&As[(p*32 + srow)*72 + scol] = av;
            uint4 bv = bval[p] ? *(const uint4*)(Xt + bbase[p] + kt*64)
                               : make_uint4(0u,0u,0u,0u);
            *(uint4*)&Bs[(p*32 + srow)*72 + scol] = bv;
        }
        __syncthreads();
        #pragma unroll
        for (int ks = 0; ks < 2; ++ks) {
            bf16x8 af[4], bfr[4];
            #pragma unroll
            for (int mi = 0; mi < 4; ++mi)
                af[mi] = *(const bf16x8*)&As[(wm*64 + mi*16 + l16)*72 + ks*32 + quad*8];
            #pragma unroll
            for (int ni = 0; ni < 4; ++ni)
                bfr[ni] = *(const bf16x8*)&Bs[(wn*64 + ni*16 + l16)*72 + ks*32 + quad*8];
            #pragma unroll
            for (int mi = 0; mi < 4; ++mi)
                #pragma unroll
                for (int ni = 0; ni < 4; ++ni)
                    acc[mi][ni] = __builtin_amdgcn_mfma_f32_16x16x32_bf16(
                        af[mi], bfr[ni], acc[mi][ni], 0, 0, 0);
        }
    }

    // epilogue: silu(c + conv_b[h]) * proj_w[h], reduce over the 128 h of this tile
    if (tid < 128) colsum[tid] = 0.f;
    __syncthreads();
    float cp[4] = {0.f, 0.f, 0.f, 0.f};
    #pragma unroll
    for (int mi = 0; mi < 4; ++mi) {
        #pragma unroll
        for (int r = 0; r < 4; ++r) {
            int h = h0 + wm*64 + mi*16 + quad*4 + r;
            float bias = conv_b[h], wgt = proj_w[h];
            #pragma unroll
            for (int ni = 0; ni < 4; ++ni) {
                float v = acc[mi][ni][r] + bias;
                float s = v / (1.f + expf(-v));
                cp[ni] += s * wgt;
            }
        }
    }
    #pragma unroll
    for (int ni = 0; ni < 4; ++ni)
        atomicAdd(&colsum[wn*64 + ni*16 + l16], cp[ni]);
    __syncthreads();
    if (tid < 128) {
        int bt = n0 + tid;
        if (bt < NCOL) atomicAdd(&rawacc[bt], colsum[tid]);
    }
}

// ---------------- softplus + time mask -> raw --------------------------------
__global__ void finalize_raw(const float* __restrict__ rawacc, const float* __restrict__ proj_b,
                             const int* __restrict__ enc_len, float* __restrict__ raw) {
    int idx = blockIdx.x*blockDim.x + threadIdx.x;
    if (idx >= NCOL) return;
    int b = idx / T_, t = idx - b*T_;
    float xv = rawacc[idx] + proj_b[0];
    float sp = (xv > 20.f) ? xv : log1pf(expf(xv));
    raw[idx] = (t < enc_len[b]) ? (sp + 1e-4f) : 0.f;
}

// ---------------- per-b: mass, scale, loss, tok, cumsum -> sw, centers -------
__global__ void scan_kernel(const float* __restrict__ raw, const int* __restrict__ tgt,
                            float* __restrict__ sw, float* __restrict__ centers,
                            float* __restrict__ out) {
    int b = blockIdx.x;
    int lane = threadIdx.x;   // 64 threads
    const float* r = raw + b*T_;
    float m = 0.f;
    for (int t = lane; t < T_; t += 64) m += r[t];
    #pragma unroll
    for (int off = 32; off > 0; off >>= 1) m += __shfl_down(m, off);
    float mass = __shfl(m, 0);
    int tok = min(max(tgt[b], 1), MAXTOK);
    if (lane == 0) {
        atomicAdd(&out[LOSS_IDX], fabsf(mass - (float)tok) * (0.25f / (float)B_));
        out[TOK_BASE + b] = (float)tok;
    }
    float scale = (float)tok / fmaxf(mass, 1e-6f);
    float running = 0.f;
    for (int t0 = 0; t0 < T_; t0 += 64) {
        int t = t0 + lane;
        float v = (t < T_) ? r[t] * scale : 0.f;
        float s = v;
        #pragma unroll
        for (int d = 1; d < 64; d <<= 1) {
            float u = __shfl_up(s, d);
            if (lane >= d) s += u;
        }
        if (t < T_) {
            sw[b*T_ + t] = v;
            centers[b*T_ + t] = running + s - 0.5f*v;
        }
        running += __shfl(s, 63);
    }
}

// ---------------- denom[b,kk] = sum_t exp(-d^2/(2T^2)) * sw -------------------
__global__ void denom_kernel(const float* __restrict__ sw, const float* __restrict__ centers,
                             float* __restrict__ denom) {
    int b = blockIdx.y;
    int kk = threadIdx.x;           // 0..191
    int t0 = blockIdx.x * 8;
    float tc = kk + 0.5f;
    float dsum = 0.f;
    #pragma unroll
    for (int j = 0; j < 8; ++j) {
        int t = t0 + j;
        if (t < T_) {
            float d = centers[b*T_ + t] - tc;
            dsum += expf(-d*d*INV2T2) * sw[b*T_ + t];
        }
    }
    atomicAdd(&denom[b*MAXTOK + kk], dsum);
}

// ---------------- acoustic[b,kk,h] = sum_t assign_norm[t,kk] * x[b,h,t] -------
__global__ __launch_bounds__(256) void einsum_kernel(
    const float* __restrict__ sw, const float* __restrict__ centers,
    const float* __restrict__ denom, const float* __restrict__ x,
    const int* __restrict__ tgt, float* __restrict__ out)
{
    __shared__ float As2[32][36];
    __shared__ float Xs[64][33];
    int b = blockIdx.z;
    int h0 = blockIdx.x * 64;
    int kk0 = blockIdx.y * 32;
    int tid = threadIdx.x;
    int tok = min(max(tgt[b], 1), MAXTOK);

    int kkl_s = tid & 31;
    int tt_s  = tid >> 5;         // 0..7
    int kk = kk0 + kkl_s;
    float invden = (kk < tok) ? 1.f / fmaxf(denom[b*MAXTOK + kk], 1e-6f) : 0.f;
    float tc = kk + 0.5f;

    int h_loc = tid & 63;
    int kkg = tid >> 6;           // 0..3; this wave's kk block = kkg*8..kkg*8+7

    float acc[8];
    #pragma unroll
    for (int r = 0; r < 8; ++r) acc[r] = 0.f;

    for (int t0 = 0; t0 < T_; t0 += 32) {
        __syncthreads();
        #pragma unroll
        for (int p = 0; p < 4; ++p) {
            int tt = p*8 + tt_s;
            int t = t0 + tt;
            float val = 0.f;
            if (t < T_) {
                float d = centers[b*T_ + t] - tc;
                val = expf(-d*d*INV2T2) * sw[b*T_ + t] * invden;
            }
            As2[tt][kkl_s] = val;
        }
        #pragma unroll
        for (int p = 0; p < 8; ++p) {
            int hh = p*8 + tt_s;
            int t = t0 + kkl_s;
            Xs[hh][kkl_s] = (t < T_) ? x[((long)b*H_ + h0 + hh)*T_ + t] : 0.f;
        }
        __syncthreads();
        #pragma unroll
        for (int tt = 0; tt < 32; ++tt) {
            float xv = Xs[h_loc][tt];
            float4 a0 = *(const float4*)&As2[tt][kkg*8];
            float4 a1 = *(const float4*)&As2[tt][kkg*8 + 4];
            acc[0] += a0.x * xv; acc[1] += a0.y * xv;
            acc[2] += a0.z * xv; acc[3] += a0.w * xv;
            acc[4] += a1.x * xv; acc[5] += a1.y * xv;
            acc[6] += a1.z * xv; acc[7] += a1.w * xv;
        }
    }
    long obase = ((long)b*MAXTOK + kk0 + kkg*8) * H_ + h0 + h_loc;
    #pragma unroll
    for (int r = 0; r < 8; ++r)
        out[obase + (long)r*H_] = acc[r];
}

extern "C" void kernel_launch(void* const* d_in, const int* in_sizes, int n_in,
                              void* d_out, int out_size, void* d_ws, size_t ws_size,
                              hipStream_t stream)
{
    const float* x      = (const float*)d_in[0];
    const int*   elen   = (const int*)d_in[1];
    const int*   tlen   = (const int*)d_in[2];
    const float* conv_w = (const float*)d_in[3];
    const float* conv_b = (const float*)d_in[4];
    const float* proj_w = (const float*)d_in[5];
    const float* proj_b = (const float*)d_in[6];
    float* out = (float*)d_out;

    unsigned short* Xt = (unsigned short*)d_ws;              // B*1502*1024 bf16
    unsigned short* Ar = Xt + (size_t)B_*TPAD*1024;          // H*3072 bf16
    float* fbase  = (float*)(Ar + (size_t)H_*KDIM);
    float* rawacc = fbase;                                   // 24000
    float* raw    = rawacc + NCOL;                           // 24000
    float* swv    = raw + NCOL;                              // 24000
    float* cen    = swv + NCOL;                              // 24000
    float* den    = cen + NCOL;                              // 3072

    int init_n = NCOL + B_*MAXTOK + 1 + B_*2048;
    init_kernel<<<(init_n + 255)/256, 256, 0, stream>>>(rawacc, den, out, Xt);
    precast_w<<<(H_*KDIM + 255)/256, 256, 0, stream>>>(conv_w, Ar);
    transpose_x<<<dim3(47, 32, 16), dim3(32, 32), 0, stream>>>(x, Xt);
    conv_gemm<<<dim3(188, 8), 256, 0, stream>>>(Ar, Xt, conv_b, proj_w, rawacc);
    finalize_raw<<<(NCOL + 255)/256, 256, 0, stream>>>(rawacc, proj_b, elen, raw);
    scan_kernel<<<B_, 64, 0, stream>>>(raw, tlen, swv, cen, out);
    denom_kernel<<<dim3(188, B_), 192, 0, stream>>>(swv, cen, den);
    einsum_kernel<<<dim3(16, 6, 16), 256, 0, stream>>>(swv, cen, den, x, tlen, out);
}

// Round 2
// 487.764 us; speedup vs baseline: 2.0015x; 2.0015x over previous
//
#include <hip/hip_runtime.h>
#include <stdint.h>

#define B_ 16
#define H_ 1024
#define T_ 1500
#define MAXTOK 192
#define NCOL (B_*T_)        /* 24000 columns (b,t) */
#define KDIM (3*H_)         /* 3072 GEMM K */
#define TPAD 1502           /* T + 2 pad rows (conv layout) */
#define TPK  1536           /* einsum K padded to 64 */
#define INV2T2 (1.0f/(2.0f*0.35f*0.35f))
#define LOSS_IDX (B_*MAXTOK*H_ + B_)
#define TOK_BASE (B_*MAXTOK*H_)

typedef __bf16 bf16x8 __attribute__((ext_vector_type(8)));
typedef float  f32x4  __attribute__((ext_vector_type(4)));
typedef __attribute__((address_space(3))) unsigned int       lds_u32;
typedef __attribute__((address_space(1))) const unsigned int g_u32;

__device__ __forceinline__ void gload_lds16(const void* g, void* l) {
    // async global->LDS, 16 B/lane; LDS dest = wave-uniform base + lane*16
    __builtin_amdgcn_global_load_lds((g_u32*)g, (lds_u32*)l, 16, 0, 0);
}

__device__ __forceinline__ unsigned short f2bf(float f) {
    unsigned int u = __float_as_uint(f);
    unsigned int r = (u + 0x7FFFu + ((u >> 16) & 1u)) >> 16;
    return (unsigned short)r;
}

// ---------------- init: zero accumulators, denoms, loss slot, Xt pad rows ----
__global__ void init_kernel(float* rawacc, float* denom, float* out, unsigned short* Xt) {
    int idx = blockIdx.x * blockDim.x + threadIdx.x;
    if (idx < NCOL) { rawacc[idx] = 0.f; return; }
    if (idx < NCOL + B_*MAXTOK) { denom[idx - NCOL] = 0.f; return; }
    if (idx == NCOL + B_*MAXTOK) { out[LOSS_IDX] = 0.f; return; }
    int j = idx - (NCOL + B_*MAXTOK + 1);
    if (j < B_*2048) {
        int b = j >> 11, r = j & 2047;
        long off = (long)b * TPAD * 1024 + ((r < 1024) ? r : (1501L*1024 + (r - 1024)));
        Xt[off] = 0;
    }
}

// ---------------- re-layout conv_w [h][i][k] -> bf16 Ar[h][k*1024 + i] -------
__global__ void precast_w(const float* __restrict__ cw, unsigned short* __restrict__ Ar) {
    int idx = blockIdx.x * blockDim.x + threadIdx.x;
    if (idx >= H_*KDIM) return;
    int h = idx / KDIM, rem = idx - h*KDIM;
    int k = rem >> 10, i = rem & 1023;
    Ar[idx] = f2bf(cw[h*KDIM + i*3 + k]);
}

// ------- transpose x [b][i][t] -> Xt[b][t+1][i] (bf16) and XtT[b][i][t+1] ----
__global__ void transpose_x(const float* __restrict__ x, unsigned short* __restrict__ Xt,
                            unsigned short* __restrict__ XtT) {
    __shared__ float tile[32][33];
    int b = blockIdx.z;
    int t = blockIdx.x*32 + threadIdx.x;
    int i = blockIdx.y*32 + threadIdx.y;
    float v = (t < T_) ? x[((long)b*H_ + i)*T_ + t] : 0.f;
    tile[threadIdx.y][threadIdx.x] = v;
    if (t < T_) XtT[((long)b*H_ + i)*TPK + t + 1] = f2bf(v);
    __syncthreads();
    int tt = blockIdx.x*32 + threadIdx.y;
    int ii = blockIdx.y*32 + threadIdx.x;
    if (tt < T_) Xt[((long)b*TPAD + tt + 1)*1024 + ii] = f2bf(tile[threadIdx.x][threadIdx.y]);
}

// ---------------- conv GEMM (m97-style: global_load_lds + swizzled LDS) ------
// C[h, bt] = sum_kk Ar[h,kk] * Xt[colbase(bt) + kk]; fused epilogue reduces
// proj_w[h]*silu(C+conv_b[h]) over the 128-h tile into rawacc[bt].
__global__ __launch_bounds__(256) void conv_gemm(
    const unsigned short* __restrict__ Ar, const unsigned short* __restrict__ Xt,
    const float* __restrict__ conv_b, const float* __restrict__ proj_w,
    float* __restrict__ rawacc)
{
    __shared__ unsigned short As[128*64];
    __shared__ unsigned short Bs[128*64];
    __shared__ float colsum[128];
    int tid = threadIdx.x;
    int n0 = blockIdx.x * 128;
    int h0 = blockIdx.y * 128;
    int w = tid >> 6, lane = tid & 63;
    int lrow = lane >> 3;                      // 0..7 within an 8-row group
    int lcol = ((lane & 7) ^ lrow) * 8;        // XOR-swizzled source column

    const unsigned short* aptr = Ar + (long)(h0 + w*32 + lrow) * KDIM + lcol;
    const unsigned short* bptr[4];
    #pragma unroll
    for (int i = 0; i < 4; ++i) {
        int bt = n0 + w*32 + i*8 + lrow;
        if (bt >= NCOL) bt = NCOL - 1;         // clamp; those columns unused
        int bb = bt / T_;
        int t  = bt - bb * T_;
        bptr[i] = Xt + ((long)bb * TPAD + t) * 1024 + lcol;
    }
    unsigned short* lAs = &As[(w*32)*64];
    unsigned short* lBs = &Bs[(w*32)*64];

    f32x4 acc[4][4];
    f32x4 zero = {0.f, 0.f, 0.f, 0.f};
    #pragma unroll
    for (int a = 0; a < 4; ++a)
        #pragma unroll
        for (int c = 0; c < 4; ++c) acc[a][c] = zero;

    int wm = w >> 1, wn = w & 1;
    int quad = lane >> 4, l16 = lane & 15;
    int sw8 = (l16 & 7) * 8;                   // fragment-read deswizzle term

    for (int kt = 0; kt < KDIM/64; ++kt) {
        __syncthreads();
        #pragma unroll
        for (int i = 0; i < 4; ++i) {
            gload_lds16(aptr + (long)i*8*KDIM + kt*64, lAs + i*8*64);
            gload_lds16(bptr[i] + kt*64,              lBs + i*8*64);
        }
        __syncthreads();
        #pragma unroll
        for (int ks = 0; ks < 2; ++ks) {
            int cofs = (ks*32 + quad*8) ^ sw8;
            bf16x8 af[4], bfr[4];
            #pragma unroll
            for (int mi = 0; mi < 4; ++mi)
                af[mi] = *(const bf16x8*)&As[(wm*64 + mi*16 + l16)*64 + cofs];
            #pragma unroll
            for (int ni = 0; ni < 4; ++ni)
                bfr[ni] = *(const bf16x8*)&Bs[(wn*64 + ni*16 + l16)*64 + cofs];
            #pragma unroll
            for (int mi = 0; mi < 4; ++mi)
                #pragma unroll
                for (int ni = 0; ni < 4; ++ni)
                    acc[mi][ni] = __builtin_amdgcn_mfma_f32_16x16x32_bf16(
                        af[mi], bfr[ni], acc[mi][ni], 0, 0, 0);
        }
    }

    // epilogue: silu(c + conv_b[h]) * proj_w[h], reduce over the 128 h of tile
    if (tid < 128) colsum[tid] = 0.f;
    __syncthreads();
    float cp[4] = {0.f, 0.f, 0.f, 0.f};
    #pragma unroll
    for (int mi = 0; mi < 4; ++mi) {
        #pragma unroll
        for (int r = 0; r < 4; ++r) {
            int h = h0 + wm*64 + mi*16 + quad*4 + r;
            float bias = conv_b[h], wgt = proj_w[h];
            #pragma unroll
            for (int ni = 0; ni < 4; ++ni) {
                float v = acc[mi][ni][r] + bias;
                float s = v / (1.f + expf(-v));
                cp[ni] += s * wgt;
            }
        }
    }
    #pragma unroll
    for (int ni = 0; ni < 4; ++ni)
        atomicAdd(&colsum[wn*64 + ni*16 + l16], cp[ni]);
    __syncthreads();
    if (tid < 128) {
        int bt = n0 + tid;
        if (bt < NCOL) atomicAdd(&rawacc[bt], colsum[tid]);
    }
}

// ---------------- softplus + time mask -> raw --------------------------------
__global__ void finalize_raw(const float* __restrict__ rawacc, const float* __restrict__ proj_b,
                             const int* __restrict__ enc_len, float* __restrict__ raw) {
    int idx = blockIdx.x*blockDim.x + threadIdx.x;
    if (idx >= NCOL) return;
    int b = idx / T_, t = idx - b*T_;
    float xv = rawacc[idx] + proj_b[0];
    float sp = (xv > 20.f) ? xv : log1pf(expf(xv));
    raw[idx] = (t < enc_len[b]) ? (sp + 1e-4f) : 0.f;
}

// ---------------- per-b: mass, scale, loss, tok, cumsum -> sw, centers -------
__global__ void scan_kernel(const float* __restrict__ raw, const int* __restrict__ tgt,
                            float* __restrict__ sw, float* __restrict__ centers,
                            float* __restrict__ out) {
    int b = blockIdx.x;
    int lane = threadIdx.x;   // 64 threads
    const float* r = raw + b*T_;
    float m = 0.f;
    for (int t = lane; t < T_; t += 64) m += r[t];
    #pragma unroll
    for (int off = 32; off > 0; off >>= 1) m += __shfl_down(m, off);
    float mass = __shfl(m, 0);
    int tok = min(max(tgt[b], 1), MAXTOK);
    if (lane == 0) {
        atomicAdd(&out[LOSS_IDX], fabsf(mass - (float)tok) * (0.25f / (float)B_));
        out[TOK_BASE + b] = (float)tok;
    }
    float scale = (float)tok / fmaxf(mass, 1e-6f);
    float running = 0.f;
    for (int t0 = 0; t0 < T_; t0 += 64) {
        int t = t0 + lane;
        float v = (t < T_) ? r[t] * scale : 0.f;
        float s = v;
        #pragma unroll
        for (int d = 1; d < 64; d <<= 1) {
            float u = __shfl_up(s, d);
            if (lane >= d) s += u;
        }
        if (t < T_) {
            sw[b*T_ + t] = v;
            centers[b*T_ + t] = running + s - 0.5f*v;
        }
        running += __shfl(s, 63);
    }
}

// ---------------- denom[b,kk] = sum_t exp(-d^2/(2T^2)) * sw -------------------
__global__ void denom_kernel(const float* __restrict__ sw, const float* __restrict__ centers,
                             float* __restrict__ denom) {
    int b = blockIdx.y;
    int kk = threadIdx.x;           // 0..191
    int t0 = blockIdx.x * 8;
    float tc = kk + 0.5f;
    float dsum = 0.f;
    #pragma unroll
    for (int j = 0; j < 8; ++j) {
        int t = t0 + j;
        if (t < T_) {
            float d = centers[b*T_ + t] - tc;
            dsum += expf(-d*d*INV2T2) * sw[b*T_ + t];
        }
    }
    atomicAdd(&denom[b*MAXTOK + kk], dsum);
}

// ---- An[b][kk][tp] = normalized assign (bf16), zero-padded in tp and kk -----
__global__ void an_kernel(const float* __restrict__ sw, const float* __restrict__ cen,
                          const float* __restrict__ den, const int* __restrict__ tgt,
                          unsigned short* __restrict__ An) {
    int idx = blockIdx.x*blockDim.x + threadIdx.x;
    if (idx >= B_*MAXTOK*TPK) return;
    int b = idx / (MAXTOK*TPK);
    int rem = idx - b*(MAXTOK*TPK);
    int kk = rem / TPK;
    int tp = rem - kk*TPK;
    int t = tp - 1;
    int tok = min(max(tgt[b], 1), MAXTOK);
    float v = 0.f;
    if (t >= 0 && t < T_ && kk < tok) {
        float d = cen[b*T_ + t] - ((float)kk + 0.5f);
        v = expf(-d*d*INV2T2) * sw[b*T_ + t] / fmaxf(den[b*MAXTOK + kk], 1e-6f);
    }
    An[idx] = f2bf(v);
}

// ---- out[b,kk,h] = sum_tp An[b,kk,tp] * XtT[b,h,tp]  (bf16 MFMA, A*B^T) -----
__global__ __launch_bounds__(256) void einsum_gemm(
    const unsigned short* __restrict__ An, const unsigned short* __restrict__ XtT,
    float* __restrict__ out)
{
    __shared__ unsigned short As2[64*64];
    __shared__ unsigned short Bs2[128*64];
    int b  = blockIdx.z;
    int kk0 = blockIdx.x * 64;
    int h0  = blockIdx.y * 128;
    int tid = threadIdx.x;
    int w = tid >> 6, lane = tid & 63;
    int lrow = lane >> 3;
    int lcol = ((lane & 7) ^ lrow) * 8;

    const unsigned short* aptr = An  + ((long)b*MAXTOK + kk0 + w*16 + lrow) * TPK + lcol;
    const unsigned short* bptr = XtT + ((long)b*H_    + h0  + w*32 + lrow) * TPK + lcol;
    unsigned short* lAs = &As2[(w*16)*64];
    unsigned short* lBs = &Bs2[(w*32)*64];

    f32x4 acc[2][4];
    f32x4 zero = {0.f, 0.f, 0.f, 0.f};
    #pragma unroll
    for (int a = 0; a < 2; ++a)
        #pragma unroll
        for (int c = 0; c < 4; ++c) acc[a][c] = zero;

    int wm = w >> 1, wn = w & 1;
    int quad = lane >> 4, l16 = lane & 15;
    int sw8 = (l16 & 7) * 8;

    for (int kt = 0; kt < TPK/64; ++kt) {
        __syncthreads();
        #pragma unroll
        for (int i = 0; i < 2; ++i)
            gload_lds16(aptr + (long)i*8*TPK + kt*64, lAs + i*8*64);
        #pragma unroll
        for (int i = 0; i < 4; ++i)
            gload_lds16(bptr + (long)i*8*TPK + kt*64, lBs + i*8*64);
        __syncthreads();
        #pragma unroll
        for (int ks = 0; ks < 2; ++ks) {
            int cofs = (ks*32 + quad*8) ^ sw8;
            bf16x8 af[2], bfr[4];
            #pragma unroll
            for (int mi = 0; mi < 2; ++mi)
                af[mi] = *(const bf16x8*)&As2[(wm*32 + mi*16 + l16)*64 + cofs];
            #pragma unroll
            for (int ni = 0; ni < 4; ++ni)
                bfr[ni] = *(const bf16x8*)&Bs2[(wn*64 + ni*16 + l16)*64 + cofs];
            #pragma unroll
            for (int mi = 0; mi < 2; ++mi)
                #pragma unroll
                for (int ni = 0; ni < 4; ++ni)
                    acc[mi][ni] = __builtin_amdgcn_mfma_f32_16x16x32_bf16(
                        af[mi], bfr[ni], acc[mi][ni], 0, 0, 0);
        }
    }

    #pragma unroll
    for (int mi = 0; mi < 2; ++mi) {
        int kk = kk0 + wm*32 + mi*16 + quad*4;
        #pragma unroll
        for (int ni = 0; ni < 4; ++ni) {
            int h = h0 + wn*64 + ni*16 + l16;
            long base = ((long)b*MAXTOK + kk)*H_ + h;
            #pragma unroll
            for (int r = 0; r < 4; ++r)
                out[base + (long)r*H_] = acc[mi][ni][r];
        }
    }
}

extern "C" void kernel_launch(void* const* d_in, const int* in_sizes, int n_in,
                              void* d_out, int out_size, void* d_ws, size_t ws_size,
                              hipStream_t stream)
{
    const float* x      = (const float*)d_in[0];
    const int*   elen   = (const int*)d_in[1];
    const int*   tlen   = (const int*)d_in[2];
    const float* conv_w = (const float*)d_in[3];
    const float* conv_b = (const float*)d_in[4];
    const float* proj_w = (const float*)d_in[5];
    const float* proj_b = (const float*)d_in[6];
    float* out = (float*)d_out;

    unsigned short* Xt  = (unsigned short*)d_ws;             // B*TPAD*1024 bf16
    unsigned short* Ar  = Xt  + (size_t)B_*TPAD*1024;        // H*KDIM bf16
    unsigned short* XtT = Ar  + (size_t)H_*KDIM;             // B*H*TPK bf16
    unsigned short* An  = XtT + (size_t)B_*H_*TPK;           // B*MAXTOK*TPK bf16
    float* fbase  = (float*)(An + (size_t)B_*MAXTOK*TPK);
    float* rawacc = fbase;                                   // 24000
    float* raw    = rawacc + NCOL;                           // 24000
    float* swv    = raw + NCOL;                              // 24000
    float* cen    = swv + NCOL;                              // 24000
    float* den    = cen + NCOL;                              // 3072

    int init_n = NCOL + B_*MAXTOK + 1 + B_*2048;
    init_kernel<<<(init_n + 255)/256, 256, 0, stream>>>(rawacc, den, out, Xt);
    precast_w<<<(H_*KDIM + 255)/256, 256, 0, stream>>>(conv_w, Ar);
    transpose_x<<<dim3(47, 32, 16), dim3(32, 32), 0, stream>>>(x, Xt, XtT);
    conv_gemm<<<dim3(188, 8), 256, 0, stream>>>(Ar, Xt, conv_b, proj_w, rawacc);
    finalize_raw<<<(NCOL + 255)/256, 256, 0, stream>>>(rawacc, proj_b, elen, raw);
    scan_kernel<<<B_, 64, 0, stream>>>(raw, tlen, swv, cen, out);
    denom_kernel<<<dim3(188, B_), 192, 0, stream>>>(swv, cen, den);
    an_kernel<<<(B_*MAXTOK*TPK + 255)/256, 256, 0, stream>>>(swv, cen, den, tlen, An);
    einsum_gemm<<<dim3(3, 8, 16), 256, 0, stream>>>(An, XtT, out);
}

// Round 3
// 459.533 us; speedup vs baseline: 2.1245x; 1.0614x over previous
//
#include <hip/hip_runtime.h>
#include <stdint.h>

#define B_ 16
#define H_ 1024
#define T_ 1500
#define MAXTOK 192
#define NCOL (B_*T_)        /* 24000 columns (b,t) */
#define KDIM (3*H_)         /* 3072 GEMM K */
#define TPAD 1502           /* T + 2 pad rows (conv layout) */
#define TPK  1536           /* einsum K padded to 64 (= 24*64) */
#define SPAD 1504           /* sw/cen per-b stride (16B aligned) */
#define INV2T2 (1.0f/(2.0f*0.35f*0.35f))
#define LOSS_IDX (B_*MAXTOK*H_ + B_)
#define TOK_BASE (B_*MAXTOK*H_)

typedef __bf16 bf16x8 __attribute__((ext_vector_type(8)));
typedef float  f32x4  __attribute__((ext_vector_type(4)));
typedef __attribute__((address_space(3))) unsigned int       lds_u32;
typedef __attribute__((address_space(1))) const unsigned int g_u32;

__device__ __forceinline__ void gload_lds16(const void* g, void* l) {
    __builtin_amdgcn_global_load_lds((g_u32*)g, (lds_u32*)l, 16, 0, 0);
}

__device__ __forceinline__ unsigned short f2bf(float f) {
    unsigned int u = __float_as_uint(f);
    unsigned int r = (u + 0x7FFFu + ((u >> 16) & 1u)) >> 16;
    return (unsigned short)r;
}

// ---------------- init: zero accumulators, denoms, loss slot, Xt pad rows ----
__global__ void init_kernel(float* rawacc, float* denom, float* out, unsigned short* Xt) {
    int idx = blockIdx.x * blockDim.x + threadIdx.x;
    if (idx < NCOL) { rawacc[idx] = 0.f; return; }
    if (idx < NCOL + B_*MAXTOK) { denom[idx - NCOL] = 0.f; return; }
    if (idx == NCOL + B_*MAXTOK) { out[LOSS_IDX] = 0.f; return; }
    int j = idx - (NCOL + B_*MAXTOK + 1);
    if (j < B_*2048) {
        int b = j >> 11, r = j & 2047;
        long off = (long)b * TPAD * 1024 + ((r < 1024) ? r : (1501L*1024 + (r - 1024)));
        Xt[off] = 0;
    }
}

// ---------------- re-layout conv_w [h][i][k] -> bf16 Ar[h][k*1024 + i] -------
__global__ void precast_w(const float* __restrict__ cw, unsigned short* __restrict__ Ar) {
    int idx = blockIdx.x * blockDim.x + threadIdx.x;
    if (idx >= H_*KDIM) return;
    int h = idx / KDIM, rem = idx - h*KDIM;
    int k = rem >> 10, i = rem & 1023;
    Ar[idx] = f2bf(cw[h*KDIM + i*3 + k]);
}

// ------- transpose x [b][i][t] -> Xt[b][t+1][i] (bf16) + XtT[b][i][t] (bf16) -
// 64x64 tiles, float4 loads, ushort4 stores; XtT written register-direct.
__global__ __launch_bounds__(256) void transpose_x(
    const float* __restrict__ x, unsigned short* __restrict__ Xt,
    unsigned short* __restrict__ XtT)
{
    __shared__ float tile[64][68];
    int b = blockIdx.z;
    int t0 = blockIdx.x * 64;
    int i0 = blockIdx.y * 64;
    int tx = threadIdx.x & 15;      // t-quad index (t = tx*4..tx*4+3)
    int ty = threadIdx.x >> 4;      // 0..15

    #pragma unroll
    for (int p = 0; p < 4; ++p) {
        int i = p*16 + ty;
        int t = t0 + tx*4;
        float4 v = make_float4(0.f, 0.f, 0.f, 0.f);
        if (t + 3 < T_) v = *(const float4*)&x[((long)b*H_ + i0 + i)*T_ + t];
        *(float4*)&tile[i][tx*4] = v;
        ushort4 u;
        u.x = f2bf(v.x); u.y = f2bf(v.y); u.z = f2bf(v.z); u.w = f2bf(v.w);
        *(ushort4*)&XtT[((long)b*H_ + i0 + i)*TPK + t] = u;
    }
    __syncthreads();
    #pragma unroll
    for (int p = 0; p < 4; ++p) {
        int t = p*16 + ty;
        if (t0 + t < T_) {
            ushort4 u;
            u.x = f2bf(tile[tx*4 + 0][t]);
            u.y = f2bf(tile[tx*4 + 1][t]);
            u.z = f2bf(tile[tx*4 + 2][t]);
            u.w = f2bf(tile[tx*4 + 3][t]);
            *(ushort4*)&Xt[((long)b*TPAD + t0 + t + 1)*1024 + i0 + tx*4] = u;
        }
    }
}

// ---------------- conv GEMM (m97-style: global_load_lds + swizzled LDS) ------
__global__ __launch_bounds__(256) void conv_gemm(
    const unsigned short* __restrict__ Ar, const unsigned short* __restrict__ Xt,
    const float* __restrict__ conv_b, const float* __restrict__ proj_w,
    float* __restrict__ rawacc)
{
    __shared__ unsigned short As[128*64];
    __shared__ unsigned short Bs[128*64];
    __shared__ float colsum[128];
    int tid = threadIdx.x;
    int n0 = blockIdx.x * 128;
    int h0 = blockIdx.y * 128;
    int w = tid >> 6, lane = tid & 63;
    int lrow = lane >> 3;
    int lcol = ((lane & 7) ^ lrow) * 8;

    const unsigned short* aptr = Ar + (long)(h0 + w*32 + lrow) * KDIM + lcol;
    const unsigned short* bptr[4];
    #pragma unroll
    for (int i = 0; i < 4; ++i) {
        int bt = n0 + w*32 + i*8 + lrow;
        if (bt >= NCOL) bt = NCOL - 1;
        int bb = bt / T_;
        int t  = bt - bb * T_;
        bptr[i] = Xt + ((long)bb * TPAD + t) * 1024 + lcol;
    }
    unsigned short* lAs = &As[(w*32)*64];
    unsigned short* lBs = &Bs[(w*32)*64];

    f32x4 acc[4][4];
    f32x4 zero = {0.f, 0.f, 0.f, 0.f};
    #pragma unroll
    for (int a = 0; a < 4; ++a)
        #pragma unroll
        for (int c = 0; c < 4; ++c) acc[a][c] = zero;

    int wm = w >> 1, wn = w & 1;
    int quad = lane >> 4, l16 = lane & 15;
    int sw8 = (l16 & 7) * 8;

    for (int kt = 0; kt < KDIM/64; ++kt) {
        __syncthreads();
        #pragma unroll
        for (int i = 0; i < 4; ++i) {
            gload_lds16(aptr + (long)i*8*KDIM + kt*64, lAs + i*8*64);
            gload_lds16(bptr[i] + kt*64,              lBs + i*8*64);
        }
        __syncthreads();
        #pragma unroll
        for (int ks = 0; ks < 2; ++ks) {
            int cofs = (ks*32 + quad*8) ^ sw8;
            bf16x8 af[4], bfr[4];
            #pragma unroll
            for (int mi = 0; mi < 4; ++mi)
                af[mi] = *(const bf16x8*)&As[(wm*64 + mi*16 + l16)*64 + cofs];
            #pragma unroll
            for (int ni = 0; ni < 4; ++ni)
                bfr[ni] = *(const bf16x8*)&Bs[(wn*64 + ni*16 + l16)*64 + cofs];
            #pragma unroll
            for (int mi = 0; mi < 4; ++mi)
                #pragma unroll
                for (int ni = 0; ni < 4; ++ni)
                    acc[mi][ni] = __builtin_amdgcn_mfma_f32_16x16x32_bf16(
                        af[mi], bfr[ni], acc[mi][ni], 0, 0, 0);
        }
    }

    if (tid < 128) colsum[tid] = 0.f;
    __syncthreads();
    float cp[4] = {0.f, 0.f, 0.f, 0.f};
    #pragma unroll
    for (int mi = 0; mi < 4; ++mi) {
        #pragma unroll
        for (int r = 0; r < 4; ++r) {
            int h = h0 + wm*64 + mi*16 + quad*4 + r;
            float bias = conv_b[h], wgt = proj_w[h];
            #pragma unroll
            for (int ni = 0; ni < 4; ++ni) {
                float v = acc[mi][ni][r] + bias;
                float s = v / (1.f + expf(-v));
                cp[ni] += s * wgt;
            }
        }
    }
    #pragma unroll
    for (int ni = 0; ni < 4; ++ni)
        atomicAdd(&colsum[wn*64 + ni*16 + l16], cp[ni]);
    __syncthreads();
    if (tid < 128) {
        int bt = n0 + tid;
        if (bt < NCOL) atomicAdd(&rawacc[bt], colsum[tid]);
    }
}

// ------ per-b: softplus+mask inline, mass, loss, tok, cumsum -> sw, centers --
__global__ void scan_kernel(const float* __restrict__ rawacc, const float* __restrict__ proj_b,
                            const int* __restrict__ elen, const int* __restrict__ tgt,
                            float* __restrict__ sw, float* __restrict__ centers,
                            float* __restrict__ out) {
    int b = blockIdx.x;
    int lane = threadIdx.x;   // 64 threads
    float pb = proj_b[0];
    int el = elen[b];
    const float* ra = rawacc + b*T_;

    float m = 0.f;
    for (int t = lane; t < T_; t += 64) {
        float xv = ra[t] + pb;
        float sp = (xv > 20.f) ? xv : log1pf(expf(xv));
        m += (t < el) ? sp + 1e-4f : 0.f;
    }
    #pragma unroll
    for (int off = 32; off > 0; off >>= 1) m += __shfl_down(m, off);
    float mass = __shfl(m, 0);
    int tok = min(max(tgt[b], 1), MAXTOK);
    if (lane == 0) {
        atomicAdd(&out[LOSS_IDX], fabsf(mass - (float)tok) * (0.25f / (float)B_));
        out[TOK_BASE + b] = (float)tok;
    }
    float scale = (float)tok / fmaxf(mass, 1e-6f);
    float running = 0.f;
    for (int t0 = 0; t0 < T_; t0 += 64) {
        int t = t0 + lane;
        float v = 0.f;
        if (t < T_) {
            float xv = ra[t] + pb;
            float sp = (xv > 20.f) ? xv : log1pf(expf(xv));
            v = ((t < el) ? sp + 1e-4f : 0.f) * scale;
        }
        float s = v;
        #pragma unroll
        for (int d = 1; d < 64; d <<= 1) {
            float u = __shfl_up(s, d);
            if (lane >= d) s += u;
        }
        if (t < T_) {
            sw[b*SPAD + t] = v;
            centers[b*SPAD + t] = running + s - 0.5f*v;
        }
        running += __shfl(s, 63);
    }
}

// ---------------- denom[b,kk] = sum_t exp(-d^2/(2T^2)) * sw ------------------
__global__ void denom_kernel(const float* __restrict__ sw, const float* __restrict__ centers,
                             float* __restrict__ denom) {
    int b = blockIdx.y;
    int kk = threadIdx.x;           // 0..191
    int t0 = blockIdx.x * 128;
    float tc = kk + 0.5f;
    float dsum = 0.f;
    for (int j = 0; j < 128; ++j) {
        int t = t0 + j;
        if (t < T_) {
            float d = centers[b*SPAD + t] - tc;
            dsum += expf(-d*d*INV2T2) * sw[b*SPAD + t];
        }
    }
    atomicAdd(&denom[b*MAXTOK + kk], dsum);
}

// ---- An[b][kk][t] = normalized assign (bf16), zero-padded; ushort4 stores ---
__global__ void an_kernel(const float* __restrict__ sw, const float* __restrict__ cen,
                          const float* __restrict__ den, const int* __restrict__ tgt,
                          unsigned short* __restrict__ An) {
    int idx = blockIdx.x*blockDim.x + threadIdx.x;
    if (idx >= B_*MAXTOK*(TPK/4)) return;
    int e4 = idx * 4;
    int b = e4 / (MAXTOK*TPK);
    int rem = e4 - b*(MAXTOK*TPK);
    int kk = rem / TPK;
    int t0 = rem - kk*TPK;
    int tok = min(max(tgt[b], 1), MAXTOK);
    ushort4 u; u.x = 0; u.y = 0; u.z = 0; u.w = 0;
    if (kk < tok) {
        float invden = 1.f / fmaxf(den[b*MAXTOK + kk], 1e-6f);
        float tc = kk + 0.5f;
        float4 cv = *(const float4*)&cen[b*SPAD + t0];
        float4 sv = *(const float4*)&sw[b*SPAD + t0];
        float c[4] = {cv.x, cv.y, cv.z, cv.w};
        float s[4] = {sv.x, sv.y, sv.z, sv.w};
        unsigned short r[4];
        #pragma unroll
        for (int j = 0; j < 4; ++j) {
            int t = t0 + j;
            float v = 0.f;
            if (t < T_) {
                float d = c[j] - tc;
                v = expf(-d*d*INV2T2) * s[j] * invden;
            }
            r[j] = f2bf(v);
        }
        u.x = r[0]; u.y = r[1]; u.z = r[2]; u.w = r[3];
    }
    *(ushort4*)&An[e4] = u;
}

// ---- out[b,kk,h] = sum_t An[b,kk,t] * XtT[b,h,t]  (bf16 MFMA, A*B^T) --------
__global__ __launch_bounds__(256) void einsum_gemm(
    const unsigned short* __restrict__ An, const unsigned short* __restrict__ XtT,
    const int* __restrict__ tgt, float* __restrict__ out)
{
    __shared__ unsigned short As2[64*64];
    __shared__ unsigned short Bs2[128*64];
    int b  = blockIdx.z;
    int kk0 = blockIdx.x * 64;
    int h0  = blockIdx.y * 128;
    int tid = threadIdx.x;
    int tok = min(max(tgt[b], 1), MAXTOK);

    if (kk0 >= tok) {   // whole tile masked -> write zeros, skip GEMM
        f32x4 z = {0.f, 0.f, 0.f, 0.f};
        #pragma unroll
        for (int i = 0; i < 8; ++i) {
            int lin = i*256 + tid;          // 0..2047
            int row = lin >> 5, c4 = lin & 31;
            *(f32x4*)&out[((long)b*MAXTOK + kk0 + row)*H_ + h0 + c4*4] = z;
        }
        return;
    }

    int w = tid >> 6, lane = tid & 63;
    int lrow = lane >> 3;
    int lcol = ((lane & 7) ^ lrow) * 8;

    const unsigned short* aptr = An  + ((long)b*MAXTOK + kk0 + w*16 + lrow) * TPK + lcol;
    const unsigned short* bptr = XtT + ((long)b*H_    + h0  + w*32 + lrow) * TPK + lcol;
    unsigned short* lAs = &As2[(w*16)*64];
    unsigned short* lBs = &Bs2[(w*32)*64];

    f32x4 acc[2][4];
    f32x4 zero = {0.f, 0.f, 0.f, 0.f};
    #pragma unroll
    for (int a = 0; a < 2; ++a)
        #pragma unroll
        for (int c = 0; c < 4; ++c) acc[a][c] = zero;

    int wm = w >> 1, wn = w & 1;
    int quad = lane >> 4, l16 = lane & 15;
    int sw8 = (l16 & 7) * 8;

    for (int kt = 0; kt < TPK/64; ++kt) {
        __syncthreads();
        #pragma unroll
        for (int i = 0; i < 2; ++i)
            gload_lds16(aptr + (long)i*8*TPK + kt*64, lAs + i*8*64);
        #pragma unroll
        for (int i = 0; i < 4; ++i)
            gload_lds16(bptr + (long)i*8*TPK + kt*64, lBs + i*8*64);
        __syncthreads();
        #pragma unroll
        for (int ks = 0; ks < 2; ++ks) {
            int cofs = (ks*32 + quad*8) ^ sw8;
            bf16x8 af[2], bfr[4];
            #pragma unroll
            for (int mi = 0; mi < 2; ++mi)
                af[mi] = *(const bf16x8*)&As2[(wm*32 + mi*16 + l16)*64 + cofs];
            #pragma unroll
            for (int ni = 0; ni < 4; ++ni)
                bfr[ni] = *(const bf16x8*)&Bs2[(wn*64 + ni*16 + l16)*64 + cofs];
            #pragma unroll
            for (int mi = 0; mi < 2; ++mi)
                #pragma unroll
                for (int ni = 0; ni < 4; ++ni)
                    acc[mi][ni] = __builtin_amdgcn_mfma_f32_16x16x32_bf16(
                        af[mi], bfr[ni], acc[mi][ni], 0, 0, 0);
        }
    }

    #pragma unroll
    for (int mi = 0; mi < 2; ++mi) {
        int kk = kk0 + wm*32 + mi*16 + quad*4;
        #pragma unroll
        for (int ni = 0; ni < 4; ++ni) {
            int h = h0 + wn*64 + ni*16 + l16;
            long base = ((long)b*MAXTOK + kk)*H_ + h;
            #pragma unroll
            for (int r = 0; r < 4; ++r)
                out[base + (long)r*H_] = acc[mi][ni][r];
        }
    }
}

extern "C" void kernel_launch(void* const* d_in, const int* in_sizes, int n_in,
                              void* d_out, int out_size, void* d_ws, size_t ws_size,
                              hipStream_t stream)
{
    const float* x      = (const float*)d_in[0];
    const int*   elen   = (const int*)d_in[1];
    const int*   tlen   = (const int*)d_in[2];
    const float* conv_w = (const float*)d_in[3];
    const float* conv_b = (const float*)d_in[4];
    const float* proj_w = (const float*)d_in[5];
    const float* proj_b = (const float*)d_in[6];
    float* out = (float*)d_out;

    unsigned short* Xt  = (unsigned short*)d_ws;             // B*TPAD*1024 bf16
    unsigned short* Ar  = Xt  + (size_t)B_*TPAD*1024;        // H*KDIM bf16
    unsigned short* XtT = Ar  + (size_t)H_*KDIM;             // B*H*TPK bf16
    unsigned short* An  = XtT + (size_t)B_*H_*TPK;           // B*MAXTOK*TPK bf16
    float* fbase  = (float*)(An + (size_t)B_*MAXTOK*TPK);
    float* rawacc = fbase;                                   // NCOL
    float* swv    = rawacc + NCOL;                           // B*SPAD
    float* cen    = swv + B_*SPAD;                           // B*SPAD
    float* den    = cen + B_*SPAD;                           // B*MAXTOK

    int init_n = NCOL + B_*MAXTOK + 1 + B_*2048;
    init_kernel<<<(init_n + 255)/256, 256, 0, stream>>>(rawacc, den, out, Xt);
    precast_w<<<(H_*KDIM + 255)/256, 256, 0, stream>>>(conv_w, Ar);
    transpose_x<<<dim3(24, 16, 16), 256, 0, stream>>>(x, Xt, XtT);
    conv_gemm<<<dim3(188, 8), 256, 0, stream>>>(Ar, Xt, conv_b, proj_w, rawacc);
    scan_kernel<<<B_, 64, 0, stream>>>(rawacc, proj_b, elen, tlen, swv, cen, out);
    denom_kernel<<<dim3(12, B_), 192, 0, stream>>>(swv, cen, den);
    an_kernel<<<(B_*MAXTOK*(TPK/4) + 255)/256, 256, 0, stream>>>(swv, cen, den, tlen, An);
    einsum_gemm<<<dim3(3, 8, 16), 256, 0, stream>>>(An, XtT, tlen, out);
}

// Round 4
// 400.897 us; speedup vs baseline: 2.4353x; 1.1463x over previous
//
#include <hip/hip_runtime.h>
#include <stdint.h>

#define B_ 16
#define H_ 1024
#define T_ 1500
#define MAXTOK 192
#define NCOL (B_*T_)        /* real columns */
#define TCOLS 1536          /* padded columns per b (12 tiles of 128) */
#define KDIM (3*H_)         /* 3072 GEMM K */
#define TPADX 1544          /* Xt rows per b: row0 zero, 1..1500 data, 1501..1543 zero */
#define TPK  1536           /* einsum K padded */
#define SPAD 1504           /* sw/cen per-b stride */
#define INV2T2 (1.0f/(2.0f*0.35f*0.35f))
#define LOSS_IDX (B_*MAXTOK*H_ + B_)
#define TOK_BASE (B_*MAXTOK*H_)

typedef __bf16 bf16x8 __attribute__((ext_vector_type(8)));
typedef float  f32x4  __attribute__((ext_vector_type(4)));
typedef __attribute__((address_space(3))) unsigned int       lds_u32;
typedef __attribute__((address_space(1))) const unsigned int g_u32;

__device__ __forceinline__ void gload_lds16(const void* g, void* l) {
    __builtin_amdgcn_global_load_lds((g_u32*)g, (lds_u32*)l, 16, 0, 0);
}

__device__ __forceinline__ unsigned short f2bf(float f) {
    unsigned int u = __float_as_uint(f);
    unsigned int r = (u + 0x7FFFu + ((u >> 16) & 1u)) >> 16;
    return (unsigned short)r;
}

// ---------------- init: zero rawacc, loss slot, Xt pad rows ------------------
__global__ void init_kernel(float* rawacc, float* out, unsigned short* Xt) {
    int idx = blockIdx.x * blockDim.x + threadIdx.x;
    if (idx < NCOL) { rawacc[idx] = 0.f; return; }
    if (idx == NCOL) { out[LOSS_IDX] = 0.f; return; }
    int j = idx - (NCOL + 1);
    if (j < B_*5632) {      // 16-B zero stores: row0 (128) + rows 1501..1543 (5504)
        int b = j / 5632, r = j - b*5632;
        long halfoff = (long)b*TPADX*1024 +
                       ((r < 128) ? (long)r*8 : (1501L*1024 + (long)(r-128)*8));
        uint4 z = make_uint4(0u,0u,0u,0u);
        *(uint4*)&Xt[halfoff] = z;
    }
}

// ---------------- re-layout conv_w [h][i][k] -> bf16 Ar[h][k*1024 + i] -------
__global__ void precast_w(const float* __restrict__ cw, unsigned short* __restrict__ Ar) {
    int idx = blockIdx.x * blockDim.x + threadIdx.x;
    if (idx >= H_*KDIM) return;
    int h = idx / KDIM, rem = idx - h*KDIM;
    int k = rem >> 10, i = rem & 1023;
    Ar[idx] = f2bf(cw[h*KDIM + i*3 + k]);
}

// ------- transpose x [b][i][t] -> Xt[b][t+1][i] (bf16) + XtT[b][i][t] (bf16) -
__global__ __launch_bounds__(256) void transpose_x(
    const float* __restrict__ x, unsigned short* __restrict__ Xt,
    unsigned short* __restrict__ XtT)
{
    __shared__ float tile[64][68];
    int b = blockIdx.z;
    int t0 = blockIdx.x * 64;
    int i0 = blockIdx.y * 64;
    int tx = threadIdx.x & 15;
    int ty = threadIdx.x >> 4;

    #pragma unroll
    for (int p = 0; p < 4; ++p) {
        int i = p*16 + ty;
        int t = t0 + tx*4;
        float4 v = make_float4(0.f, 0.f, 0.f, 0.f);
        if (t + 3 < T_) v = *(const float4*)&x[((long)b*H_ + i0 + i)*T_ + t];
        *(float4*)&tile[i][tx*4] = v;
        ushort4 u;
        u.x = f2bf(v.x); u.y = f2bf(v.y); u.z = f2bf(v.z); u.w = f2bf(v.w);
        *(ushort4*)&XtT[((long)b*H_ + i0 + i)*TPK + t] = u;
    }
    __syncthreads();
    #pragma unroll
    for (int p = 0; p < 4; ++p) {
        int t = p*16 + ty;
        if (t0 + t < T_) {
            ushort4 u;
            u.x = f2bf(tile[tx*4 + 0][t]);
            u.y = f2bf(tile[tx*4 + 1][t]);
            u.z = f2bf(tile[tx*4 + 2][t]);
            u.w = f2bf(tile[tx*4 + 3][t]);
            *(ushort4*)&Xt[((long)b*TPADX + t0 + t + 1)*1024 + i0 + tx*4] = u;
        }
    }
}

// ---------------- conv GEMM: c-major K-loop, shared 136-row B window ---------
// Per i-chunk c (64 K-elems), stage Xt rows [t0 .. t0+135] once; kk=0..2 read
// B fragments at LDS row +kk. XCD-affine block mapping for L2 locality.
__global__ __launch_bounds__(256) void conv_gemm(
    const unsigned short* __restrict__ Ar, const unsigned short* __restrict__ Xt,
    const float* __restrict__ conv_b, const float* __restrict__ proj_w,
    float* __restrict__ rawacc)
{
    __shared__ unsigned short As[128*64];
    __shared__ unsigned short Bs[136*64];
    __shared__ float colsum[128];
    int bid = blockIdx.x;
    int xcd = bid & 7;
    int j = bid >> 3;            // 0..191
    int h_idx = j / 24;          // 0..7
    int g = j - h_idx*24;        // 0..23
    int n_idx = xcd*24 + g;      // 0..191
    int bb = n_idx / 12;
    int t0 = (n_idx - bb*12) * 128;
    int h0 = h_idx * 128;

    int tid = threadIdx.x;
    int w = tid >> 6, lane = tid & 63;
    int lrow = lane >> 3;
    int lcol = ((lane & 7) ^ lrow) * 8;

    const unsigned short* aptr = Ar + (long)(h0 + w*32 + lrow) * KDIM + lcol;
    const unsigned short* bX   = Xt + ((long)bb*TPADX + t0 + lrow) * 1024 + lcol;
    unsigned short* lAs = &As[(w*32)*64];

    f32x4 acc[4][4];
    f32x4 zero = {0.f, 0.f, 0.f, 0.f};
    #pragma unroll
    for (int a = 0; a < 4; ++a)
        #pragma unroll
        for (int c = 0; c < 4; ++c) acc[a][c] = zero;

    int wm = w >> 1, wn = w & 1;
    int quad = lane >> 4, l16 = lane & 15;
    int sw8a = (l16 & 7) * 8;

    for (int c = 0; c < 16; ++c) {
        __syncthreads();                       // previous-c B readers done
        for (int s = w; s < 17; s += 4)        // stage 136 B rows
            gload_lds16(bX + (long)s*8*1024 + c*64, &Bs[s*8*64]);
        #pragma unroll
        for (int kk = 0; kk < 3; ++kk) {
            if (kk) __syncthreads();           // previous-kk A readers done
            #pragma unroll
            for (int i = 0; i < 4; ++i)        // stage 128 A rows (L2-hot)
                gload_lds16(aptr + (long)i*8*KDIM + kk*1024 + c*64, lAs + i*8*64);
            __syncthreads();                   // drain staging
            int sw8b = ((l16 + kk) & 7) * 8;
            #pragma unroll
            for (int ks = 0; ks < 2; ++ks) {
                int base = ks*32 + quad*8;
                int cofa = base ^ sw8a;
                int cofb = base ^ sw8b;
                bf16x8 af[4], bfr[4];
                #pragma unroll
                for (int mi = 0; mi < 4; ++mi)
                    af[mi] = *(const bf16x8*)&As[(wm*64 + mi*16 + l16)*64 + cofa];
                #pragma unroll
                for (int ni = 0; ni < 4; ++ni)
                    bfr[ni] = *(const bf16x8*)&Bs[(wn*64 + ni*16 + l16 + kk)*64 + cofb];
                #pragma unroll
                for (int mi = 0; mi < 4; ++mi)
                    #pragma unroll
                    for (int ni = 0; ni < 4; ++ni)
                        acc[mi][ni] = __builtin_amdgcn_mfma_f32_16x16x32_bf16(
                            af[mi], bfr[ni], acc[mi][ni], 0, 0, 0);
            }
        }
    }

    // epilogue: silu(c + conv_b[h]) * proj_w[h], reduce over 128 h of the tile
    if (tid < 128) colsum[tid] = 0.f;
    __syncthreads();
    float cp[4] = {0.f, 0.f, 0.f, 0.f};
    #pragma unroll
    for (int mi = 0; mi < 4; ++mi) {
        #pragma unroll
        for (int r = 0; r < 4; ++r) {
            int h = h0 + wm*64 + mi*16 + quad*4 + r;
            float bias = conv_b[h], wgt = proj_w[h];
            #pragma unroll
            for (int ni = 0; ni < 4; ++ni) {
                float v = acc[mi][ni][r] + bias;
                float s = v / (1.f + expf(-v));
                cp[ni] += s * wgt;
            }
        }
    }
    #pragma unroll
    for (int ni = 0; ni < 4; ++ni)
        atomicAdd(&colsum[wn*64 + ni*16 + l16], cp[ni]);
    __syncthreads();
    if (tid < 128) {
        int t = t0 + tid;
        if (t < T_) atomicAdd(&rawacc[bb*T_ + t], colsum[tid]);
    }
}

// ------ per-b: softplus+mask inline, mass, loss, tok, cumsum -> sw, centers --
__global__ void scan_kernel(const float* __restrict__ rawacc, const float* __restrict__ proj_b,
                            const int* __restrict__ elen, const int* __restrict__ tgt,
                            float* __restrict__ sw, float* __restrict__ centers,
                            float* __restrict__ out) {
    int b = blockIdx.x;
    int lane = threadIdx.x;   // 64 threads
    float pb = proj_b[0];
    int el = elen[b];
    const float* ra = rawacc + b*T_;

    float m = 0.f;
    for (int t = lane; t < T_; t += 64) {
        float xv = ra[t] + pb;
        float sp = (xv > 20.f) ? xv : log1pf(expf(xv));
        m += (t < el) ? sp + 1e-4f : 0.f;
    }
    #pragma unroll
    for (int off = 32; off > 0; off >>= 1) m += __shfl_down(m, off);
    float mass = __shfl(m, 0);
    int tok = min(max(tgt[b], 1), MAXTOK);
    if (lane == 0) {
        atomicAdd(&out[LOSS_IDX], fabsf(mass - (float)tok) * (0.25f / (float)B_));
        out[TOK_BASE + b] = (float)tok;
    }
    float scale = (float)tok / fmaxf(mass, 1e-6f);
    float running = 0.f;
    for (int t0 = 0; t0 < T_; t0 += 64) {
        int t = t0 + lane;
        float v = 0.f;
        if (t < T_) {
            float xv = ra[t] + pb;
            float sp = (xv > 20.f) ? xv : log1pf(expf(xv));
            v = ((t < el) ? sp + 1e-4f : 0.f) * scale;
        }
        float s = v;
        #pragma unroll
        for (int d = 1; d < 64; d <<= 1) {
            float u = __shfl_up(s, d);
            if (lane >= d) s += u;
        }
        if (t < T_) {
            sw[b*SPAD + t] = v;
            centers[b*SPAD + t] = running + s - 0.5f*v;
        }
        running += __shfl(s, 63);
    }
}

// ---- fused denom + An: one block per (b,kk); exps stashed in LDS ------------
__global__ __launch_bounds__(256) void denom_an(
    const float* __restrict__ sw, const float* __restrict__ cen,
    const int* __restrict__ tgt, unsigned short* __restrict__ An)
{
    __shared__ float ebuf[TPK];
    __shared__ float wsum[4];
    __shared__ float dsh;
    int kk = blockIdx.x;
    int b  = blockIdx.y;
    int tid = threadIdx.x;
    int tok = min(max(tgt[b], 1), MAXTOK);
    bool live = (kk < tok);
    float tc = kk + 0.5f;

    float lsum = 0.f;
    for (int t = tid; t < TPK; t += 256) {
        float e = 0.f;
        if (live && t < T_) {
            float d = cen[b*SPAD + t] - tc;
            e = expf(-d*d*INV2T2) * sw[b*SPAD + t];
        }
        ebuf[t] = e;
        lsum += e;
    }
    #pragma unroll
    for (int off = 32; off > 0; off >>= 1) lsum += __shfl_down(lsum, off);
    if ((tid & 63) == 0) wsum[tid >> 6] = lsum;
    __syncthreads();
    if (tid == 0) dsh = 1.f / fmaxf(wsum[0] + wsum[1] + wsum[2] + wsum[3], 1e-6f);
    __syncthreads();
    float invden = dsh;

    unsigned short* dst = An + ((long)b*MAXTOK + kk) * TPK;
    for (int q = tid; q < TPK/4; q += 256) {
        ushort4 u;
        u.x = f2bf(ebuf[q*4 + 0] * invden);
        u.y = f2bf(ebuf[q*4 + 1] * invden);
        u.z = f2bf(ebuf[q*4 + 2] * invden);
        u.w = f2bf(ebuf[q*4 + 3] * invden);
        *(ushort4*)&dst[q*4] = u;
    }
}

// ---- out[b,kk,h] = sum_t An[b,kk,t] * XtT[b,h,t]  (bf16 MFMA, A*B^T) --------
__global__ __launch_bounds__(256) void einsum_gemm(
    const unsigned short* __restrict__ An, const unsigned short* __restrict__ XtT,
    const int* __restrict__ tgt, float* __restrict__ out)
{
    __shared__ unsigned short As2[64*64];
    __shared__ unsigned short Bs2[128*64];
    int b  = blockIdx.z;
    int kk0 = blockIdx.x * 64;
    int h0  = blockIdx.y * 128;
    int tid = threadIdx.x;
    int tok = min(max(tgt[b], 1), MAXTOK);

    if (kk0 >= tok) {   // whole tile masked -> write zeros, skip GEMM
        f32x4 z = {0.f, 0.f, 0.f, 0.f};
        #pragma unroll
        for (int i = 0; i < 8; ++i) {
            int lin = i*256 + tid;
            int row = lin >> 5, c4 = lin & 31;
            *(f32x4*)&out[((long)b*MAXTOK + kk0 + row)*H_ + h0 + c4*4] = z;
        }
        return;
    }

    int w = tid >> 6, lane = tid & 63;
    int lrow = lane >> 3;
    int lcol = ((lane & 7) ^ lrow) * 8;

    const unsigned short* aptr = An  + ((long)b*MAXTOK + kk0 + w*16 + lrow) * TPK + lcol;
    const unsigned short* bptr = XtT + ((long)b*H_    + h0  + w*32 + lrow) * TPK + lcol;
    unsigned short* lAs = &As2[(w*16)*64];
    unsigned short* lBs = &Bs2[(w*32)*64];

    f32x4 acc[2][4];
    f32x4 zero = {0.f, 0.f, 0.f, 0.f};
    #pragma unroll
    for (int a = 0; a < 2; ++a)
        #pragma unroll
        for (int c = 0; c < 4; ++c) acc[a][c] = zero;

    int wm = w >> 1, wn = w & 1;
    int quad = lane >> 4, l16 = lane & 15;
    int sw8 = (l16 & 7) * 8;

    for (int kt = 0; kt < TPK/64; ++kt) {
        __syncthreads();
        #pragma unroll
        for (int i = 0; i < 2; ++i)
            gload_lds16(aptr + (long)i*8*TPK + kt*64, lAs + i*8*64);
        #pragma unroll
        for (int i = 0; i < 4; ++i)
            gload_lds16(bptr + (long)i*8*TPK + kt*64, lBs + i*8*64);
        __syncthreads();
        #pragma unroll
        for (int ks = 0; ks < 2; ++ks) {
            int cofs = (ks*32 + quad*8) ^ sw8;
            bf16x8 af[2], bfr[4];
            #pragma unroll
            for (int mi = 0; mi < 2; ++mi)
                af[mi] = *(const bf16x8*)&As2[(wm*32 + mi*16 + l16)*64 + cofs];
            #pragma unroll
            for (int ni = 0; ni < 4; ++ni)
                bfr[ni] = *(const bf16x8*)&Bs2[(wn*64 + ni*16 + l16)*64 + cofs];
            #pragma unroll
            for (int mi = 0; mi < 2; ++mi)
                #pragma unroll
                for (int ni = 0; ni < 4; ++ni)
                    acc[mi][ni] = __builtin_amdgcn_mfma_f32_16x16x32_bf16(
                        af[mi], bfr[ni], acc[mi][ni], 0, 0, 0);
        }
    }

    #pragma unroll
    for (int mi = 0; mi < 2; ++mi) {
        int kk = kk0 + wm*32 + mi*16 + quad*4;
        #pragma unroll
        for (int ni = 0; ni < 4; ++ni) {
            int h = h0 + wn*64 + ni*16 + l16;
            long base = ((long)b*MAXTOK + kk)*H_ + h;
            #pragma unroll
            for (int r = 0; r < 4; ++r)
                out[base + (long)r*H_] = acc[mi][ni][r];
        }
    }
}

extern "C" void kernel_launch(void* const* d_in, const int* in_sizes, int n_in,
                              void* d_out, int out_size, void* d_ws, size_t ws_size,
                              hipStream_t stream)
{
    const float* x      = (const float*)d_in[0];
    const int*   elen   = (const int*)d_in[1];
    const int*   tlen   = (const int*)d_in[2];
    const float* conv_w = (const float*)d_in[3];
    const float* conv_b = (const float*)d_in[4];
    const float* proj_w = (const float*)d_in[5];
    const float* proj_b = (const float*)d_in[6];
    float* out = (float*)d_out;

    unsigned short* Xt  = (unsigned short*)d_ws;             // B*TPADX*1024 bf16
    unsigned short* Ar  = Xt  + (size_t)B_*TPADX*1024;       // H*KDIM bf16
    unsigned short* XtT = Ar  + (size_t)H_*KDIM;             // B*H*TPK bf16
    unsigned short* An  = XtT + (size_t)B_*H_*TPK;           // B*MAXTOK*TPK bf16
    float* fbase  = (float*)(An + (size_t)B_*MAXTOK*TPK);
    float* rawacc = fbase;                                   // NCOL
    float* swv    = rawacc + NCOL;                           // B*SPAD
    float* cen    = swv + B_*SPAD;                           // B*SPAD

    int init_n = NCOL + 1 + B_*5632;
    init_kernel<<<(init_n + 255)/256, 256, 0, stream>>>(rawacc, out, Xt);
    precast_w<<<(H_*KDIM + 255)/256, 256, 0, stream>>>(conv_w, Ar);
    transpose_x<<<dim3(24, 16, 16), 256, 0, stream>>>(x, Xt, XtT);
    conv_gemm<<<1536, 256, 0, stream>>>(Ar, Xt, conv_b, proj_w, rawacc);
    scan_kernel<<<B_, 64, 0, stream>>>(rawacc, proj_b, elen, tlen, swv, cen, out);
    denom_an<<<dim3(MAXTOK, B_), 256, 0, stream>>>(swv, cen, tlen, An);
    einsum_gemm<<<dim3(3, 8, 16), 256, 0, stream>>>(An, XtT, tlen, out);
}